// Round 4
// baseline (1354.937 us; speedup 1.0000x reference)
//
#include <hip/hip_runtime.h>
#include <hip/hip_bf16.h>
#include <hip/hip_cooperative_groups.h>
#include <math.h>

namespace cg = cooperative_groups;

// LiquidNeuralNetwork: B=4096, IN=512, HS={256,128,64}, S=64, OUT=12
// Round 17: collapse proj0 -> fold -> proj1 -> proj2 -> latfinal into ONE
// persistent cooperative kernel (grid.sync between phases). 6 launches -> 2.
// Phase bodies are the r16-verified kernels verbatim (same math, same memory
// layout); act table loaded to LDS once. Fallback to r16 sequence if the
// cooperative launch is rejected.

#define BATCH 4096

typedef __bf16 bf16x8 __attribute__((ext_vector_type(8)));
typedef float floatx4 __attribute__((ext_vector_type(4)));

__device__ __forceinline__ void gl_lds16(const void* g, void* l) {
    __builtin_amdgcn_global_load_lds(
        (const __attribute__((address_space(1))) void*)g,
        (__attribute__((address_space(3))) void*)l, 16, 0, 0);
}

__device__ __forceinline__ float act_exact(float v) {
    return tanhf(v) + 0.1f * sinf(0.5f * v) * cosf(0.3f * v);
}

// ---------- merged conversion pre-pass + table build ----------
// a != nullptr: scale row d = k0+r by a[d] (builds G = a-scaled weights).

__device__ __forceinline__ void wconv_tile(const float* __restrict__ Wi,
                                           __hip_bfloat16* __restrict__ Wt,
                                           const float* __restrict__ a,
                                           int K, int n, int k0, int t)
{
    __shared__ float lds[64][65];
    const float* src = Wi + ((size_t)n * K + k0) * 64;
#pragma unroll
    for (int i = 0; i < 4; ++i) {
        int idx = t + i * 256;
        int r = idx >> 4;
        int s4 = (idx & 15) * 4;
        float4 v = *(const float4*)(src + (size_t)r * 64 + s4);
        if (a) {
            float av = a[k0 + r];
            v.x *= av; v.y *= av; v.z *= av; v.w *= av;
        }
        lds[s4 + 0][r] = v.x;
        lds[s4 + 1][r] = v.y;
        lds[s4 + 2][r] = v.z;
        lds[s4 + 3][r] = v.w;
    }
    __syncthreads();
    __hip_bfloat16* dst = Wt + (size_t)n * 64 * K + k0;
#pragma unroll
    for (int i = 0; i < 4; ++i) {
        int idx = t + i * 256;
        int s = idx >> 4;
        int k4 = (idx & 15) * 4;
        union { ushort4 u4; __hip_bfloat16 b[4]; } o;
        o.b[0] = __float2bfloat16(lds[s][k4 + 0]);
        o.b[1] = __float2bfloat16(lds[s][k4 + 1]);
        o.b[2] = __float2bfloat16(lds[s][k4 + 2]);
        o.b[3] = __float2bfloat16(lds[s][k4 + 3]);
        *(ushort4*)(dst + (size_t)s * K + k4) = o.u4;
    }
}

// [0,2048): xconv; [2048,4096): Wi0; [4096,4608): Wi1*a0; [4608,4736): Wi2*a1;
// 4736: act table; [4737,4801): L0->bf16; [4801,4817): L1->bf16.
__global__ __launch_bounds__(256) void conv_all(
    const float* __restrict__ x, __hip_bfloat16* __restrict__ xb,
    const float* __restrict__ Wi0, const float* __restrict__ Wi1,
    const float* __restrict__ Wi2,
    const float* __restrict__ a0, const float* __restrict__ a1,
    const float* __restrict__ L0, const float* __restrict__ L1,
    __hip_bfloat16* __restrict__ Wt0, __hip_bfloat16* __restrict__ G1,
    __hip_bfloat16* __restrict__ G2,
    __hip_bfloat16* __restrict__ Lb0, __hip_bfloat16* __restrict__ Lb1,
    float* __restrict__ Tg)
{
    int bid = blockIdx.x;
    int t = threadIdx.x;
    if (bid < 2048) {
        int g = bid * 256 + t;
        float4 v = ((const float4*)x)[g];
        union { ushort4 u4; __hip_bfloat16 b[4]; } o;
        o.b[0] = __float2bfloat16(v.x);
        o.b[1] = __float2bfloat16(v.y);
        o.b[2] = __float2bfloat16(v.z);
        o.b[3] = __float2bfloat16(v.w);
        ((ushort4*)xb)[g] = o.u4;
    } else if (bid < 4096) {
        int r = bid - 2048;
        wconv_tile(Wi0, Wt0, nullptr, 512, r >> 3, (r & 7) * 64, t);
    } else if (bid < 4608) {
        int r = bid - 4096;
        wconv_tile(Wi1, G1, a0, 256, r >> 2, (r & 3) * 64, t);
    } else if (bid < 4736) {
        int r = bid - 4608;
        wconv_tile(Wi2, G2, a1, 128, r >> 1, (r & 1) * 64, t);
    } else if (bid == 4736) {
#pragma unroll
        for (int i = 0; i < 2; ++i) {
            int e = t + 256 * i;          // [0,512)
            float v0 = (float)(e - 256) * 0.03125f;
            Tg[2 * e] = act_exact(v0);
            Tg[2 * e + 1] = act_exact(v0 + 0.03125f);
        }
    } else if (bid < 4801) {
        int g = (bid - 4737) * 1024 + t * 4;       // 65536 elems
        float4 v = *(const float4*)(L0 + g);
        union { ushort4 u4; __hip_bfloat16 b[4]; } o;
        o.b[0] = __float2bfloat16(v.x);
        o.b[1] = __float2bfloat16(v.y);
        o.b[2] = __float2bfloat16(v.z);
        o.b[3] = __float2bfloat16(v.w);
        *(ushort4*)(Lb0 + g) = o.u4;
    } else {
        int g = (bid - 4801) * 1024 + t * 4;       // 16384 elems
        float4 v = *(const float4*)(L1 + g);
        union { ushort4 u4; __hip_bfloat16 b[4]; } o;
        o.b[0] = __float2bfloat16(v.x);
        o.b[1] = __float2bfloat16(v.y);
        o.b[2] = __float2bfloat16(v.z);
        o.b[3] = __float2bfloat16(v.w);
        *(ushort4*)(Lb1 + g) = o.u4;
    }
}

// ---------- proj tile (r16-verified body, bid = tile index) ----------

__device__ __forceinline__ void proj_tile(
    int bid, const __hip_bfloat16* __restrict__ X,
    const __hip_bfloat16* __restrict__ Wt,
    const float* __restrict__ bi, const float* __restrict__ bl,
    const float* __restrict__ Wo, const float* __restrict__ bo,
    __hip_bfloat16* __restrict__ t, int K, int Nn,
    __hip_bfloat16* As, __hip_bfloat16* Bs, const float* Tt)
{
    const int tid = threadIdx.x;
    const int wid = tid >> 6;
    const int wb = wid & 1;               // batch half (64 rows each)
    const int wn = wid >> 1;              // neuron within block [0,4)
    const int lane = tid & 63;
    const int m = lane & 15;
    const int qd = lane >> 4;

    const int xcd = bid & 7;
    const int sw = bid >> 3;
    const int n_grp = sw >> 2;
    const int row_grp = ((sw & 3) << 3) | xcd;   // [0,32)
    const int row0 = row_grp * 128;
    const int n0 = n_grp * 4;
    const int n = n0 + wn;

    floatx4 acc[4][4];
#pragma unroll
    for (int rt = 0; rt < 4; ++rt) {
        int sb = n * 64 + rt * 16 + qd * 4;
        float4 b4i = *(const float4*)(bi + sb);
        float4 b4l = *(const float4*)(bl + sb);
        floatx4 b4 = {b4i.x + b4l.x, b4i.y + b4l.y, b4i.z + b4l.z, b4i.w + b4l.w};
#pragma unroll
        for (int ct = 0; ct < 4; ++ct)
            acc[rt][ct] = b4;
    }

    const int ar0 = tid >> 3;
    const int aq0 = (tid & 7) ^ (ar0 & 7);
    const int ar1 = (tid + 512) >> 3;
    const int aq1 = ((tid + 512) & 7) ^ (ar1 & 7);
    const __hip_bfloat16* Xr0 = X + (size_t)(row0 + ar0) * K + aq0 * 8;
    const __hip_bfloat16* Xr1 = X + (size_t)(row0 + ar1) * K + aq1 * 8;

    const __hip_bfloat16* bsrc[4];
#pragma unroll
    for (int i = 0; i < 4; ++i) {
        int Li = i * 512 + tid;
        int c = Li >> 3;                 // s-row [0,256)
        int q = (Li & 7) ^ (c & 7);
        bsrc[i] = Wt + ((size_t)(n0 + (c >> 6)) * 64 + (c & 63)) * K + q * 8;
    }

    for (int k0 = 0; k0 < K; k0 += 64) {
        gl_lds16(Xr0 + k0, (void*)(As + tid * 8));
        gl_lds16(Xr1 + k0, (void*)(As + ((size_t)tid + 512) * 8));
#pragma unroll
        for (int i = 0; i < 4; ++i)
            gl_lds16(bsrc[i] + k0, (void*)(Bs + ((size_t)i * 512 + tid) * 8));
        __syncthreads();
#pragma unroll
        for (int kk = 0; kk < 2; ++kk) {
            bf16x8 af[4], bfr[4];
#pragma unroll
            for (int rt = 0; rt < 4; ++rt) {          // A = Wt s-rows
                int sr = wn * 64 + rt * 16 + m;
                int slot = sr * 8 + ((kk * 4 + qd) ^ (sr & 7));
                af[rt] = *(const bf16x8*)(Bs + slot * 8);
            }
#pragma unroll
            for (int ct = 0; ct < 4; ++ct) {          // B = X batch-rows
                int br = wb * 64 + ct * 16 + m;
                int slot = br * 8 + ((kk * 4 + qd) ^ (br & 7));
                bfr[ct] = *(const bf16x8*)(As + slot * 8);
            }
#pragma unroll
            for (int rt = 0; rt < 4; ++rt)
#pragma unroll
                for (int ct = 0; ct < 4; ++ct)
                    acc[rt][ct] = __builtin_amdgcn_mfma_f32_16x16x32_bf16(
                        af[rt], bfr[ct], acc[rt][ct], 0, 0, 0);
        }
        __syncthreads();
    }

    float wo[4][4];
#pragma unroll
    for (int rt = 0; rt < 4; ++rt) {
        float4 w4 = *(const float4*)(Wo + n * 64 + rt * 16 + qd * 4);
        wo[rt][0] = w4.x; wo[rt][1] = w4.y; wo[rt][2] = w4.z; wo[rt][3] = w4.w;
    }
    float bov = bo[n];
    float p[4] = {0.f, 0.f, 0.f, 0.f};
    const float2* Tt2 = (const float2*)Tt;
#pragma unroll
    for (int ct = 0; ct < 4; ++ct)
#pragma unroll
        for (int rt = 0; rt < 4; ++rt)
#pragma unroll
            for (int reg = 0; reg < 4; ++reg) {
                float v = acc[rt][ct][reg];
                float u = fmaf(v, 32.f, 256.f);
                u = fminf(fmaxf(u, 0.f), 510.99f);
                float fi = floorf(u);
                int ii = (int)fi;
                float fr = u - fi;
                float2 pr = Tt2[ii];
                p[ct] = fmaf(fmaf(fr, pr.y - pr.x, pr.x), wo[rt][reg], p[ct]);
            }
#pragma unroll
    for (int ct = 0; ct < 4; ++ct) {
        p[ct] += __shfl_xor(p[ct], 16, 64);
        p[ct] += __shfl_xor(p[ct], 32, 64);
    }
    if (qd == 0) {
#pragma unroll
        for (int ct = 0; ct < 4; ++ct)
            t[(size_t)(row0 + wb * 64 + ct * 16 + m) * Nn + n] =
                __float2bfloat16(p[ct] + bov);
    }
}

// ---------- fold tile: W' = G + 0.1 * (G @ L^T) (r16-verified body) ----------

__device__ __forceinline__ void fold_tile(
    int bid,
    const __hip_bfloat16* __restrict__ G1, const __hip_bfloat16* __restrict__ Lb0,
    __hip_bfloat16* __restrict__ W1,
    const __hip_bfloat16* __restrict__ G2, const __hip_bfloat16* __restrict__ Lb1,
    __hip_bfloat16* __restrict__ W2,
    __hip_bfloat16* As, __hip_bfloat16* Bs)
{
    const __hip_bfloat16* G;
    const __hip_bfloat16* Lb;
    __hip_bfloat16* W;
    int r0, e0, K;
    if (bid < 64) {
        G = G1; Lb = Lb0; W = W1; K = 256;
        r0 = (bid >> 1) * 256; e0 = (bid & 1) * 128;
    } else {
        G = G2; Lb = Lb1; W = W2; K = 128;
        r0 = (bid - 64) * 256; e0 = 0;
    }

    const int tid = threadIdx.x;
    const int wid = tid >> 6;
    const int wb = wid & 1;
    const int wn = wid >> 1;
    const int lane = tid & 63;
    const int m = lane & 15;
    const int qd = lane >> 4;

    floatx4 acc[4][4];
#pragma unroll
    for (int rt = 0; rt < 4; ++rt)
#pragma unroll
        for (int ct = 0; ct < 4; ++ct)
            acc[rt][ct] = {0.f, 0.f, 0.f, 0.f};

    const int ar0 = tid >> 3;
    const int aq0 = (tid & 7) ^ (ar0 & 7);
    const int ar1 = (tid + 512) >> 3;
    const int aq1 = ((tid + 512) & 7) ^ (ar1 & 7);
    const __hip_bfloat16* Xr0 = Lb + (size_t)(e0 + ar0) * K + aq0 * 8;
    const __hip_bfloat16* Xr1 = Lb + (size_t)(e0 + ar1) * K + aq1 * 8;

    const __hip_bfloat16* bsrc[4];
#pragma unroll
    for (int i = 0; i < 4; ++i) {
        int Li = i * 512 + tid;
        int c = Li >> 3;
        int q = (Li & 7) ^ (c & 7);
        bsrc[i] = G + (size_t)(r0 + c) * K + q * 8;
    }

    for (int k0 = 0; k0 < K; k0 += 64) {
        gl_lds16(Xr0 + k0, (void*)(As + tid * 8));
        gl_lds16(Xr1 + k0, (void*)(As + ((size_t)tid + 512) * 8));
#pragma unroll
        for (int i = 0; i < 4; ++i)
            gl_lds16(bsrc[i] + k0, (void*)(Bs + ((size_t)i * 512 + tid) * 8));
        __syncthreads();
#pragma unroll
        for (int kk = 0; kk < 2; ++kk) {
            bf16x8 af[4], bfr[4];
#pragma unroll
            for (int rt = 0; rt < 4; ++rt) {
                int sr = wn * 64 + rt * 16 + m;
                int slot = sr * 8 + ((kk * 4 + qd) ^ (sr & 7));
                af[rt] = *(const bf16x8*)(Bs + slot * 8);
            }
#pragma unroll
            for (int ct = 0; ct < 4; ++ct) {
                int br = wb * 64 + ct * 16 + m;
                int slot = br * 8 + ((kk * 4 + qd) ^ (br & 7));
                bfr[ct] = *(const bf16x8*)(As + slot * 8);
            }
#pragma unroll
            for (int rt = 0; rt < 4; ++rt)
#pragma unroll
                for (int ct = 0; ct < 4; ++ct)
                    acc[rt][ct] = __builtin_amdgcn_mfma_f32_16x16x32_bf16(
                        af[rt], bfr[ct], acc[rt][ct], 0, 0, 0);
        }
        __syncthreads();
    }

#pragma unroll
    for (int rt = 0; rt < 4; ++rt)
#pragma unroll
        for (int ct = 0; ct < 4; ++ct)
#pragma unroll
            for (int reg = 0; reg < 4; ++reg) {
                int rl = wn * 64 + rt * 16 + qd * 4 + reg;
                int el = wb * 64 + ct * 16 + m;
                size_t gi = (size_t)(r0 + rl) * K + (e0 + el);
                W[gi] = __float2bfloat16(
                    __bfloat162float(G[gi]) + 0.1f * acc[rt][ct][reg]);
            }
}

// ---------- final lateral + output head, 512-thread pair variant ----------

__device__ __forceinline__ void latfinal_pair(
    int pr, const __hip_bfloat16* __restrict__ t2,
    const float* __restrict__ Lm, const float* __restrict__ av,
    const float* __restrict__ Wout, const float* __restrict__ bout,
    float* __restrict__ y, __hip_bfloat16* AsRaw, __hip_bfloat16* BsRaw)
{
    const int tid = threadIdx.x;
    const int sub = tid >> 8;                  // which 16-row tile
    const int st = tid & 255;
    float* tbT = (float*)BsRaw + sub * (64 * 20);   // [64][20]
    float* hb  = (float*)AsRaw + sub * (16 * 65);   // [16][65]
    const int row0 = pr * 32 + sub * 16;

#pragma unroll
    for (int i = 0; i < 4; ++i) {
        int idx = st + i * 256;
        int r = idx >> 6;
        int c = idx & 63;
        tbT[c * 20 + r] = __bfloat162float(t2[(size_t)(row0 + r) * 64 + c]);
    }
    __syncthreads();

    const int c = st & 63;
    const int rb = (st >> 6) * 4;
    float acc[4] = {0.f, 0.f, 0.f, 0.f};
    for (int mm = 0; mm < 64; ++mm) {
        float lv = Lm[mm * 64 + c];
        float4 tv = *(const float4*)&tbT[mm * 20 + rb];
        acc[0] += tv.x * lv; acc[1] += tv.y * lv;
        acc[2] += tv.z * lv; acc[3] += tv.w * lv;
    }
    float a = av[c];
#pragma unroll
    for (int r = 0; r < 4; ++r)
        hb[(rb + r) * 65 + c] = (tbT[c * 20 + rb + r] + 0.1f * acc[r]) * a;
    __syncthreads();
    if (st < 192) {
        int r = st / 12, o = st - 12 * r;
        float accy = bout[o];
#pragma unroll
        for (int k = 0; k < 64; ++k)
            accy += hb[r * 65 + k] * Wout[k * 12 + o];
        y[(size_t)(row0 + r) * 12 + o] = accy;
    }
}

// ---------- persistent cooperative mega-kernel ----------

struct MegaArgs {
    const __hip_bfloat16* xb;  const __hip_bfloat16* Wt0;
    const __hip_bfloat16* G1;  const __hip_bfloat16* Lb0; __hip_bfloat16* W1f;
    const __hip_bfloat16* G2;  const __hip_bfloat16* Lb1; __hip_bfloat16* W2f;
    __hip_bfloat16* t0; __hip_bfloat16* t1; __hip_bfloat16* t2;
    const float* bi0; const float* bl0; const float* Wo0; const float* bo0;
    const float* bi1; const float* bl1; const float* Wo1; const float* bo1;
    const float* bi2; const float* bl2; const float* Wo2; const float* bo2;
    const float* Tg; const float* Lfin; const float* afin;
    const float* Wout; const float* bout; float* y;
};

__global__ __launch_bounds__(512, 6) void liquid_mega(MegaArgs a)
{
    cg::grid_group grid = cg::this_grid();
    __shared__ __align__(16) __hip_bfloat16 As[128 * 64];   // 16 KB
    __shared__ __align__(16) __hip_bfloat16 Bs[256 * 64];   // 32 KB
    __shared__ __align__(16) float Tt[1024];                // 4 KB

    const int G = gridDim.x;
    const int bid0 = blockIdx.x;

    if (threadIdx.x < 256)
        gl_lds16(a.Tg + threadIdx.x * 4, (void*)(Tt + threadIdx.x * 4));
    __syncthreads();   // drains vmcnt; Tt valid for all phases

    // phase A: layer-0 projection (2048 tiles)
    for (int tile = bid0; tile < 2048; tile += G)
        proj_tile(tile, a.xb, a.Wt0, a.bi0, a.bl0, a.Wo0, a.bo0,
                  a.t0, 512, 256, As, Bs, Tt);
    __threadfence(); grid.sync();

    // phase B: lateral fold (80 tiles) — xb/Wt0 regions now dead
    for (int tile = bid0; tile < 80; tile += G)
        fold_tile(tile, a.G1, a.Lb0, a.W1f, a.G2, a.Lb1, a.W2f, As, Bs);
    __threadfence(); grid.sync();

    // phase C: layer-1 projection (1024 tiles)
    for (int tile = bid0; tile < 1024; tile += G)
        proj_tile(tile, a.t0, a.W1f, a.bi1, a.bl1, a.Wo1, a.bo1,
                  a.t1, 256, 128, As, Bs, Tt);
    __threadfence(); grid.sync();

    // phase D: layer-2 projection (512 tiles)
    for (int tile = bid0; tile < 512; tile += G)
        proj_tile(tile, a.t1, a.W2f, a.bi2, a.bl2, a.Wo2, a.bo2,
                  a.t2, 128, 64, As, Bs, Tt);
    __threadfence(); grid.sync();

    // phase E: final lateral + output head (128 pairs of 16-row tiles)
    for (int pr = bid0; pr < 128; pr += G)
        latfinal_pair(pr, a.t2, a.Lfin, a.afin, a.Wout, a.bout, a.y, As, Bs);
}

// ---------- standalone kernels (fallback if coop launch rejected) ----------

__global__ __launch_bounds__(512, 4) void liquid_proj_mfma(
    const __hip_bfloat16* __restrict__ X, const __hip_bfloat16* __restrict__ Wt,
    const float* __restrict__ bi, const float* __restrict__ bl,
    const float* __restrict__ Wo, const float* __restrict__ bo,
    const float* __restrict__ Tg, __hip_bfloat16* __restrict__ t, int K, int Nn)
{
    __shared__ __align__(16) __hip_bfloat16 As[128 * 64];
    __shared__ __align__(16) __hip_bfloat16 Bs[256 * 64];
    __shared__ __align__(16) float Tt[1024];
    if (threadIdx.x < 256)
        gl_lds16(Tg + threadIdx.x * 4, (void*)(Tt + threadIdx.x * 4));
    proj_tile(blockIdx.x, X, Wt, bi, bl, Wo, bo, t, K, Nn, As, Bs, Tt);
}

__global__ __launch_bounds__(512, 4) void fold_lateral(
    const __hip_bfloat16* __restrict__ G1, const __hip_bfloat16* __restrict__ Lb0,
    __hip_bfloat16* __restrict__ W1,
    const __hip_bfloat16* __restrict__ G2, const __hip_bfloat16* __restrict__ Lb1,
    __hip_bfloat16* __restrict__ W2)
{
    __shared__ __align__(16) __hip_bfloat16 As[128 * 64];
    __shared__ __align__(16) __hip_bfloat16 Bs[256 * 64];
    fold_tile(blockIdx.x, G1, Lb0, W1, G2, Lb1, W2, As, Bs);
}

__global__ __launch_bounds__(512) void lateral_final(
    const __hip_bfloat16* __restrict__ t2, const float* __restrict__ Lm,
    const float* __restrict__ a, const float* __restrict__ Wout,
    const float* __restrict__ bout, float* __restrict__ y)
{
    __shared__ __align__(16) __hip_bfloat16 As[128 * 64];
    __shared__ __align__(16) __hip_bfloat16 Bs[256 * 64];
    latfinal_pair(blockIdx.x, t2, Lm, a, Wout, bout, y, As, Bs);
}

// ---------- fp32 fallback path (round-2 verified) ----------

__global__ __launch_bounds__(256) void liquid_proj_f32(
    const float* __restrict__ x, const float* __restrict__ Wi,
    const float* __restrict__ bi, const float* __restrict__ bl,
    const float* __restrict__ Wo, const float* __restrict__ bo,
    float* __restrict__ t, int K, int Nn)
{
    __shared__ float xs[16][65];
    __shared__ float ws[16][65];
    const int tid = threadIdx.x;
    const int tx = tid & 15, ty = tid >> 4;
    const int row0 = blockIdx.x * 64;
    const int n = blockIdx.y;
    const float* Wn = Wi + (size_t)n * K * 64;
    float acc[4][4] = {};
    for (int k0 = 0; k0 < K; k0 += 16) {
#pragma unroll
        for (int i = 0; i < 4; ++i) {
            int li = tid + 256 * i;
            xs[li & 15][li >> 4] = x[(size_t)(row0 + (li >> 4)) * K + k0 + (li & 15)];
        }
#pragma unroll
        for (int i = 0; i < 4; ++i) {
            int li = tid + 256 * i;
            ws[li >> 6][li & 63] = Wn[(size_t)(k0 + (li >> 6)) * 64 + (li & 63)];
        }
        __syncthreads();
#pragma unroll
        for (int kk = 0; kk < 16; ++kk) {
            float xa[4], wb[4];
#pragma unroll
            for (int i = 0; i < 4; ++i) xa[i] = xs[kk][4 * ty + i];
#pragma unroll
            for (int j = 0; j < 4; ++j) wb[j] = ws[kk][4 * tx + j];
#pragma unroll
            for (int i = 0; i < 4; ++i)
#pragma unroll
                for (int j = 0; j < 4; ++j) acc[i][j] += xa[i] * wb[j];
        }
        __syncthreads();
    }
    float part[4] = {0.f, 0.f, 0.f, 0.f};
#pragma unroll
    for (int j = 0; j < 4; ++j) {
        int cc = 4 * tx + j;
        float bias = bi[n * 64 + cc] + bl[n * 64 + cc];
        float wov = Wo[n * 64 + cc];
#pragma unroll
        for (int i = 0; i < 4; ++i) {
            float v = acc[i][j] + bias;
            part[i] += (tanhf(v) + 0.1f * sinf(0.5f * v) * cosf(0.3f * v)) * wov;
        }
    }
#pragma unroll
    for (int mk = 1; mk < 16; mk <<= 1)
#pragma unroll
        for (int i = 0; i < 4; ++i) part[i] += __shfl_xor(part[i], mk, 64);
    if (tx == 0) {
        float b = bo[n];
#pragma unroll
        for (int i = 0; i < 4; ++i)
            t[(size_t)(row0 + 4 * ty + i) * Nn + n] = part[i] + b;
    }
}

__global__ void lateral_f32_kernel(const float* __restrict__ t,
                                   const float* __restrict__ L,
                                   const float* __restrict__ a,
                                   float* __restrict__ h, int Nn)
{
    extern __shared__ float tb[];
    const int b = blockIdx.x;
    const int n = threadIdx.x;
    tb[n] = t[(size_t)b * Nn + n];
    __syncthreads();
    float acc = 0.f;
    for (int mm = 0; mm < Nn; ++mm)
        acc += tb[mm] * L[(size_t)mm * Nn + n];
    h[(size_t)b * Nn + n] = (tb[n] + 0.1f * acc) * a[n];
}

__global__ void out_f32_kernel(const float* __restrict__ h,
                               const float* __restrict__ Wout,
                               const float* __restrict__ bout,
                               float* __restrict__ y)
{
    int g = blockIdx.x * blockDim.x + threadIdx.x;
    if (g >= BATCH * 12) return;
    int b = g / 12, o = g - 12 * b;
    float acc = bout[o];
    const float* hb = h + (size_t)b * 64;
#pragma unroll
    for (int k = 0; k < 64; ++k) acc += hb[k] * Wout[k * 12 + o];
    y[g] = acc;
}

extern "C" void kernel_launch(void* const* d_in, const int* in_sizes, int n_in,
                              void* d_out, int out_size, void* d_ws, size_t ws_size,
                              hipStream_t stream)
{
    (void)in_sizes; (void)n_in; (void)out_size;
    const float* x = (const float*)d_in[0];
    const float* Wout = (const float*)d_in[22];
    const float* bout = (const float*)d_in[23];
    const int dims[4] = {512, 256, 128, 64};
    char* ws = (char*)d_ws;
    const size_t MB = 1024u * 1024u;
    const size_t KB = 1024u;

    if (ws_size >= 28 * MB) {
        // Layout (28 MB) — identical to r16 (verified):
        //   [0,16)   Wt0 ; after phase A: t1 @0 (1MB), W2f @2 (1MB), t2 @4
        //   [16,20)  G1 ; [20,21) G2 ; [21,25) xb -> W1f after phase A
        //   [25,27)  t0 ; [27,..) Tg, Lb0, Lb1
        __hip_bfloat16* Wt0 = (__hip_bfloat16*)ws;
        __hip_bfloat16* G1  = (__hip_bfloat16*)(ws + 16 * MB);
        __hip_bfloat16* G2  = (__hip_bfloat16*)(ws + 20 * MB);
        __hip_bfloat16* xb  = (__hip_bfloat16*)(ws + 21 * MB);
        __hip_bfloat16* W1f = (__hip_bfloat16*)(ws + 21 * MB);
        __hip_bfloat16* t0  = (__hip_bfloat16*)(ws + 25 * MB);
        __hip_bfloat16* t1  = (__hip_bfloat16*)ws;
        __hip_bfloat16* W2f = (__hip_bfloat16*)(ws + 2 * MB);
        __hip_bfloat16* t2  = (__hip_bfloat16*)(ws + 4 * MB);
        float* Tg = (float*)(ws + 27 * MB);
        __hip_bfloat16* Lb0 = (__hip_bfloat16*)(ws + 27 * MB + 16 * KB);
        __hip_bfloat16* Lb1 = (__hip_bfloat16*)(ws + 27 * MB + 160 * KB);

        const float* a0 = (const float*)d_in[7];
        const float* a1 = (const float*)d_in[14];
        const float* L0 = (const float*)d_in[6];
        const float* L1 = (const float*)d_in[13];

        conv_all<<<4817, 256, 0, stream>>>(
            x, xb, (const float*)d_in[1], (const float*)d_in[8],
            (const float*)d_in[15], a0, a1, L0, L1,
            Wt0, G1, G2, Lb0, Lb1, Tg);

        MegaArgs ma;
        ma.xb = xb;  ma.Wt0 = Wt0;
        ma.G1 = G1;  ma.Lb0 = Lb0; ma.W1f = W1f;
        ma.G2 = G2;  ma.Lb1 = Lb1; ma.W2f = W2f;
        ma.t0 = t0;  ma.t1 = t1;   ma.t2 = t2;
        ma.bi0 = (const float*)d_in[2];  ma.bl0 = (const float*)d_in[3];
        ma.Wo0 = (const float*)d_in[4];  ma.bo0 = (const float*)d_in[5];
        ma.bi1 = (const float*)d_in[9];  ma.bl1 = (const float*)d_in[10];
        ma.Wo1 = (const float*)d_in[11]; ma.bo1 = (const float*)d_in[12];
        ma.bi2 = (const float*)d_in[16]; ma.bl2 = (const float*)d_in[17];
        ma.Wo2 = (const float*)d_in[18]; ma.bo2 = (const float*)d_in[19];
        ma.Tg = Tg;
        ma.Lfin = (const float*)d_in[20]; ma.afin = (const float*)d_in[21];
        ma.Wout = Wout; ma.bout = bout; ma.y = (float*)d_out;

        static int s_maxB = -1;
        if (s_maxB < 0) {
            int mb = 0;
            if (hipOccupancyMaxActiveBlocksPerMultiprocessor(
                    &mb, liquid_mega, 512, 0) != hipSuccess || mb <= 0)
                mb = 2;
            int ncu = 0;
            if (hipDeviceGetAttribute(&ncu, hipDeviceAttributeMultiprocessorCount,
                                      0) != hipSuccess || ncu <= 0)
                ncu = 256;
            s_maxB = mb * ncu;
            if (s_maxB > 2048) s_maxB = 2048;
            s_maxB &= ~7;                      // keep %8 == 0 for XCD swizzle
            if (s_maxB < 8) s_maxB = 8;
        }

        void* kp[] = { &ma };
        hipError_t ce = hipLaunchCooperativeKernel(
            liquid_mega, dim3(s_maxB), dim3(512), kp, 0u, stream);
        if (ce != hipSuccess) {
            // fallback: r16-verified 5-kernel sequence
            liquid_proj_mfma<<<2048, 512, 0, stream>>>(
                xb, Wt0, ma.bi0, ma.bl0, ma.Wo0, ma.bo0, Tg, t0, 512, 256);
            fold_lateral<<<80, 512, 0, stream>>>(G1, Lb0, W1f, G2, Lb1, W2f);
            liquid_proj_mfma<<<1024, 512, 0, stream>>>(
                t0, W1f, ma.bi1, ma.bl1, ma.Wo1, ma.bo1, Tg, t1, 256, 128);
            liquid_proj_mfma<<<512, 512, 0, stream>>>(
                t1, W2f, ma.bi2, ma.bl2, ma.Wo2, ma.bo2, Tg, t2, 128, 64);
            lateral_final<<<128, 512, 0, stream>>>(
                t2, ma.Lfin, ma.afin, Wout, bout, (float*)d_out);
        }
    } else {
        float* tbufs[3] = {(float*)ws, (float*)ws, (float*)(ws + 4 * MB)};
        float* hs[3] = {(float*)(ws + 4 * MB), (float*)(ws + 2 * MB),
                        (float*)(ws + 5 * MB)};
        const float* prev = x;
        for (int l = 0; l < 3; ++l) {
            const float* Wi = (const float*)d_in[1 + 7 * l + 0];
            const float* bi = (const float*)d_in[1 + 7 * l + 1];
            const float* bl = (const float*)d_in[1 + 7 * l + 2];
            const float* Wo = (const float*)d_in[1 + 7 * l + 3];
            const float* bo = (const float*)d_in[1 + 7 * l + 4];
            const float* L  = (const float*)d_in[1 + 7 * l + 5];
            const float* a  = (const float*)d_in[1 + 7 * l + 6];
            const int K = dims[l], Nn = dims[l + 1];
            liquid_proj_f32<<<dim3(BATCH / 64, Nn), 256, 0, stream>>>(
                prev, Wi, bi, bl, Wo, bo, tbufs[l], K, Nn);
            lateral_f32_kernel<<<BATCH, Nn, Nn * sizeof(float), stream>>>(
                tbufs[l], L, a, hs[l], Nn);
            prev = hs[l];
        }
        out_f32_kernel<<<(BATCH * 12 + 255) / 256, 256, 0, stream>>>(
            hs[2], Wout, bout, (float*)d_out);
    }
}

// Round 6
// 245.910 us; speedup vs baseline: 5.5099x; 5.5099x over previous
//
#include <hip/hip_runtime.h>
#include <hip/hip_bf16.h>
#include <math.h>

// LiquidNeuralNetwork: B=4096, IN=512, HS={256,128,64}, S=64, OUT=12
// Round 19: cooperative mega-kernel line abandoned (r17 ran via preemption
// thrash, r18 hung — grid.sync beyond guaranteed co-residency is illegal).
// Back to the r16-verified 254.1us chain, plus the final head folded:
//   y = t2 @ Wfin + bout,  Wfin = (I + 0.1 L2) diag(a2) Wout  (64x12 f32,
// precomputed in conv_all). latfinal's 64x64 lateral loop becomes a trivial
// 64x12 GEMM. Chain: conv_all -> proj0 -> fold -> proj1 -> proj2 -> out_head.

#define BATCH 4096

typedef __bf16 bf16x8 __attribute__((ext_vector_type(8)));
typedef float floatx4 __attribute__((ext_vector_type(4)));

__device__ __forceinline__ void gl_lds16(const void* g, void* l) {
    __builtin_amdgcn_global_load_lds(
        (const __attribute__((address_space(1))) void*)g,
        (__attribute__((address_space(3))) void*)l, 16, 0, 0);
}

__device__ __forceinline__ float act_exact(float v) {
    return tanhf(v) + 0.1f * sinf(0.5f * v) * cosf(0.3f * v);
}

// ---------- merged conversion pre-pass + table build ----------
// a != nullptr: scale row d = k0+r by a[d] (builds G = a-scaled weights).

__device__ __forceinline__ void wconv_tile(const float* __restrict__ Wi,
                                           __hip_bfloat16* __restrict__ Wt,
                                           const float* __restrict__ a,
                                           int K, int n, int k0, int t)
{
    __shared__ float lds[64][65];
    const float* src = Wi + ((size_t)n * K + k0) * 64;
#pragma unroll
    for (int i = 0; i < 4; ++i) {
        int idx = t + i * 256;
        int r = idx >> 4;
        int s4 = (idx & 15) * 4;
        float4 v = *(const float4*)(src + (size_t)r * 64 + s4);
        if (a) {
            float av = a[k0 + r];
            v.x *= av; v.y *= av; v.z *= av; v.w *= av;
        }
        lds[s4 + 0][r] = v.x;
        lds[s4 + 1][r] = v.y;
        lds[s4 + 2][r] = v.z;
        lds[s4 + 3][r] = v.w;
    }
    __syncthreads();
    __hip_bfloat16* dst = Wt + (size_t)n * 64 * K + k0;
#pragma unroll
    for (int i = 0; i < 4; ++i) {
        int idx = t + i * 256;
        int s = idx >> 4;
        int k4 = (idx & 15) * 4;
        union { ushort4 u4; __hip_bfloat16 b[4]; } o;
        o.b[0] = __float2bfloat16(lds[s][k4 + 0]);
        o.b[1] = __float2bfloat16(lds[s][k4 + 1]);
        o.b[2] = __float2bfloat16(lds[s][k4 + 2]);
        o.b[3] = __float2bfloat16(lds[s][k4 + 3]);
        *(ushort4*)(dst + (size_t)s * K + k4) = o.u4;
    }
}

// [0,2048): xconv; [2048,4096): Wi0; [4096,4608): Wi1*a0; [4608,4736): Wi2*a1;
// 4736: act table; [4737,4801): L0->bf16; [4801,4817): L1->bf16;
// 4817: Wfin = (I + 0.1 L2) diag(a2) Wout  (64x12 f32).
__global__ __launch_bounds__(256) void conv_all(
    const float* __restrict__ x, __hip_bfloat16* __restrict__ xb,
    const float* __restrict__ Wi0, const float* __restrict__ Wi1,
    const float* __restrict__ Wi2,
    const float* __restrict__ a0, const float* __restrict__ a1,
    const float* __restrict__ L0, const float* __restrict__ L1,
    const float* __restrict__ L2, const float* __restrict__ a2,
    const float* __restrict__ Wout,
    __hip_bfloat16* __restrict__ Wt0, __hip_bfloat16* __restrict__ G1,
    __hip_bfloat16* __restrict__ G2,
    __hip_bfloat16* __restrict__ Lb0, __hip_bfloat16* __restrict__ Lb1,
    float* __restrict__ Tg, float* __restrict__ Wfin)
{
    int bid = blockIdx.x;
    int t = threadIdx.x;
    if (bid < 2048) {
        int g = bid * 256 + t;
        float4 v = ((const float4*)x)[g];
        union { ushort4 u4; __hip_bfloat16 b[4]; } o;
        o.b[0] = __float2bfloat16(v.x);
        o.b[1] = __float2bfloat16(v.y);
        o.b[2] = __float2bfloat16(v.z);
        o.b[3] = __float2bfloat16(v.w);
        ((ushort4*)xb)[g] = o.u4;
    } else if (bid < 4096) {
        int r = bid - 2048;
        wconv_tile(Wi0, Wt0, nullptr, 512, r >> 3, (r & 7) * 64, t);
    } else if (bid < 4608) {
        int r = bid - 4096;
        wconv_tile(Wi1, G1, a0, 256, r >> 2, (r & 3) * 64, t);
    } else if (bid < 4736) {
        int r = bid - 4608;
        wconv_tile(Wi2, G2, a1, 128, r >> 1, (r & 1) * 64, t);
    } else if (bid == 4736) {
#pragma unroll
        for (int i = 0; i < 2; ++i) {
            int e = t + 256 * i;          // [0,512)
            float v0 = (float)(e - 256) * 0.03125f;
            Tg[2 * e] = act_exact(v0);
            Tg[2 * e + 1] = act_exact(v0 + 0.03125f);
        }
    } else if (bid < 4801) {
        int g = (bid - 4737) * 1024 + t * 4;       // 65536 elems
        float4 v = *(const float4*)(L0 + g);
        union { ushort4 u4; __hip_bfloat16 b[4]; } o;
        o.b[0] = __float2bfloat16(v.x);
        o.b[1] = __float2bfloat16(v.y);
        o.b[2] = __float2bfloat16(v.z);
        o.b[3] = __float2bfloat16(v.w);
        *(ushort4*)(Lb0 + g) = o.u4;
    } else if (bid < 4817) {
        int g = (bid - 4801) * 1024 + t * 4;       // 16384 elems
        float4 v = *(const float4*)(L1 + g);
        union { ushort4 u4; __hip_bfloat16 b[4]; } o;
        o.b[0] = __float2bfloat16(v.x);
        o.b[1] = __float2bfloat16(v.y);
        o.b[2] = __float2bfloat16(v.z);
        o.b[3] = __float2bfloat16(v.w);
        *(ushort4*)(Lb1 + g) = o.u4;
    } else {
        // Wfin[m][o] = a2[m]*Wout[m][o] + 0.1 * sum_n L2[m][n]*a2[n]*Wout[n][o]
#pragma unroll
        for (int i = 0; i < 3; ++i) {
            int e = t + 256 * i;                   // [0,768)
            int mm = e / 12, o = e - 12 * mm;
            float acc = a2[mm] * Wout[mm * 12 + o];
            float s = 0.f;
            for (int nn = 0; nn < 64; ++nn)
                s += L2[mm * 64 + nn] * a2[nn] * Wout[nn * 12 + o];
            Wfin[e] = acc + 0.1f * s;
        }
    }
}

// ---------- MFMA proj (r16-verified) ----------
// Block: 512 threads = 8 waves (2 batch-halves x 4 neurons); 128 batch x 4 n.
// Per-wave tile 64s x 64b: acc[4][4]. TRANSPOSED (A=Wt, B=X):
// D[s = rt*16+qd*4+reg][b = wb*64+ct*16+m]. In-register Wo-dot, 2-shfl reduce.

__global__ __launch_bounds__(512, 4) void liquid_proj_mfma(
    const __hip_bfloat16* __restrict__ X,   // [B][K] bf16
    const __hip_bfloat16* __restrict__ Wt,  // [Nn][64][K] bf16
    const float* __restrict__ bi, const float* __restrict__ bl,
    const float* __restrict__ Wo, const float* __restrict__ bo,
    const float* __restrict__ Tg,           // [1024] float2-pair table
    __hip_bfloat16* __restrict__ t, int K, int Nn)
{
    __shared__ __align__(16) __hip_bfloat16 As[128 * 64];   // 16 KB (X tile)
    __shared__ __align__(16) __hip_bfloat16 Bs[256 * 64];   // 32 KB (Wt tile)
    __shared__ __align__(16) float Tt[1024];                // 4 KB

    const int tid = threadIdx.x;
    const int wid = tid >> 6;
    const int wb = wid & 1;               // batch half (64 rows each)
    const int wn = wid >> 1;              // neuron within block [0,4)
    const int lane = tid & 63;
    const int m = lane & 15;
    const int qd = lane >> 4;

    // swizzle: bid = (n_grp*4 + row_local)*8 + xcd ; row_grp = row_local*8+xcd
    const int bid = blockIdx.x;
    const int xcd = bid & 7;
    const int sw = bid >> 3;
    const int n_grp = sw >> 2;
    const int row_grp = ((sw & 3) << 3) | xcd;   // [0,32)
    const int row0 = row_grp * 128;
    const int n0 = n_grp * 4;
    const int n = n0 + wn;

    // table -> LDS: 256 16B chunks
    if (tid < 256)
        gl_lds16(Tg + tid * 4, (void*)(Tt + tid * 4));

    // bias folded into acc init; s = rt*16 + qd*4 + reg (same for all ct)
    floatx4 acc[4][4];
#pragma unroll
    for (int rt = 0; rt < 4; ++rt) {
        int sb = n * 64 + rt * 16 + qd * 4;
        float4 b4i = *(const float4*)(bi + sb);
        float4 b4l = *(const float4*)(bl + sb);
        floatx4 b4 = {b4i.x + b4l.x, b4i.y + b4l.y, b4i.z + b4l.z, b4i.w + b4l.w};
#pragma unroll
        for (int ct = 0; ct < 4; ++ct)
            acc[rt][ct] = b4;
    }

    // A(X) staging: 1024 chunks, 2/thread; slot c, source chunk (r, q^(r&7))
    const int ar0 = tid >> 3;
    const int aq0 = (tid & 7) ^ (ar0 & 7);
    const int ar1 = (tid + 512) >> 3;
    const int aq1 = ((tid + 512) & 7) ^ (ar1 & 7);
    const __hip_bfloat16* Xr0 = X + (size_t)(row0 + ar0) * K + aq0 * 8;
    const __hip_bfloat16* Xr1 = X + (size_t)(row0 + ar1) * K + aq1 * 8;

    // B(Wt) staging: 2048 chunks, 4/thread
    const __hip_bfloat16* bsrc[4];
#pragma unroll
    for (int i = 0; i < 4; ++i) {
        int Li = i * 512 + tid;
        int c = Li >> 3;                 // s-row [0,256)
        int q = (Li & 7) ^ (c & 7);
        bsrc[i] = Wt + ((size_t)(n0 + (c >> 6)) * 64 + (c & 63)) * K + q * 8;
    }

    for (int k0 = 0; k0 < K; k0 += 64) {
        gl_lds16(Xr0 + k0, (void*)(As + tid * 8));
        gl_lds16(Xr1 + k0, (void*)(As + ((size_t)tid + 512) * 8));
#pragma unroll
        for (int i = 0; i < 4; ++i)
            gl_lds16(bsrc[i] + k0, (void*)(Bs + ((size_t)i * 512 + tid) * 8));
        __syncthreads();
#pragma unroll
        for (int kk = 0; kk < 2; ++kk) {
            bf16x8 af[4], bfr[4];
#pragma unroll
            for (int rt = 0; rt < 4; ++rt) {          // A = Wt s-rows
                int sr = wn * 64 + rt * 16 + m;
                int slot = sr * 8 + ((kk * 4 + qd) ^ (sr & 7));
                af[rt] = *(const bf16x8*)(Bs + slot * 8);
            }
#pragma unroll
            for (int ct = 0; ct < 4; ++ct) {          // B = X batch-rows
                int br = wb * 64 + ct * 16 + m;
                int slot = br * 8 + ((kk * 4 + qd) ^ (br & 7));
                bfr[ct] = *(const bf16x8*)(As + slot * 8);
            }
#pragma unroll
            for (int rt = 0; rt < 4; ++rt)
#pragma unroll
                for (int ct = 0; ct < 4; ++ct)
                    acc[rt][ct] = __builtin_amdgcn_mfma_f32_16x16x32_bf16(
                        af[rt], bfr[ct], acc[rt][ct], 0, 0, 0);
        }
        __syncthreads();
    }

    // Epilogue: s = rt*16+qd*4+reg, b = wb*64+ct*16+m. In-register Wo-dot.
    float wo[4][4];
#pragma unroll
    for (int rt = 0; rt < 4; ++rt) {
        float4 w4 = *(const float4*)(Wo + n * 64 + rt * 16 + qd * 4);
        wo[rt][0] = w4.x; wo[rt][1] = w4.y; wo[rt][2] = w4.z; wo[rt][3] = w4.w;
    }
    float bov = bo[n];
    float p[4] = {0.f, 0.f, 0.f, 0.f};
    const float2* Tt2 = (const float2*)Tt;
#pragma unroll
    for (int ct = 0; ct < 4; ++ct)
#pragma unroll
        for (int rt = 0; rt < 4; ++rt)
#pragma unroll
            for (int reg = 0; reg < 4; ++reg) {
                float v = acc[rt][ct][reg];
                float u = fmaf(v, 32.f, 256.f);
                u = fminf(fmaxf(u, 0.f), 510.99f);
                float fi = floorf(u);
                int ii = (int)fi;
                float fr = u - fi;
                float2 pr = Tt2[ii];
                p[ct] = fmaf(fmaf(fr, pr.y - pr.x, pr.x), wo[rt][reg], p[ct]);
            }
#pragma unroll
    for (int ct = 0; ct < 4; ++ct) {
        p[ct] += __shfl_xor(p[ct], 16, 64);
        p[ct] += __shfl_xor(p[ct], 32, 64);
    }
    if (qd == 0) {
#pragma unroll
        for (int ct = 0; ct < 4; ++ct)
            t[(size_t)(row0 + wb * 64 + ct * 16 + m) * Nn + n] =
                __float2bfloat16(p[ct] + bov);
    }
}

// ---------- lateral weight fold: W' = G + 0.1 * (G @ L^T) (r16-verified) ----

__global__ __launch_bounds__(512, 4) void fold_lateral(
    const __hip_bfloat16* __restrict__ G1, const __hip_bfloat16* __restrict__ Lb0,
    __hip_bfloat16* __restrict__ W1,
    const __hip_bfloat16* __restrict__ G2, const __hip_bfloat16* __restrict__ Lb1,
    __hip_bfloat16* __restrict__ W2)
{
    __shared__ __align__(16) __hip_bfloat16 As[128 * 64];   // Lb tile
    __shared__ __align__(16) __hip_bfloat16 Bs[256 * 64];   // G tile

    const int bid = blockIdx.x;
    const __hip_bfloat16* G;
    const __hip_bfloat16* Lb;
    __hip_bfloat16* W;
    int r0, e0, K;
    if (bid < 64) {
        G = G1; Lb = Lb0; W = W1; K = 256;
        r0 = (bid >> 1) * 256; e0 = (bid & 1) * 128;
    } else {
        G = G2; Lb = Lb1; W = W2; K = 128;
        r0 = (bid - 64) * 256; e0 = 0;
    }

    const int tid = threadIdx.x;
    const int wid = tid >> 6;
    const int wb = wid & 1;
    const int wn = wid >> 1;
    const int lane = tid & 63;
    const int m = lane & 15;
    const int qd = lane >> 4;

    floatx4 acc[4][4];
#pragma unroll
    for (int rt = 0; rt < 4; ++rt)
#pragma unroll
        for (int ct = 0; ct < 4; ++ct)
            acc[rt][ct] = {0.f, 0.f, 0.f, 0.f};

    const int ar0 = tid >> 3;
    const int aq0 = (tid & 7) ^ (ar0 & 7);
    const int ar1 = (tid + 512) >> 3;
    const int aq1 = ((tid + 512) & 7) ^ (ar1 & 7);
    const __hip_bfloat16* Xr0 = Lb + (size_t)(e0 + ar0) * K + aq0 * 8;
    const __hip_bfloat16* Xr1 = Lb + (size_t)(e0 + ar1) * K + aq1 * 8;

    const __hip_bfloat16* bsrc[4];
#pragma unroll
    for (int i = 0; i < 4; ++i) {
        int Li = i * 512 + tid;
        int c = Li >> 3;
        int q = (Li & 7) ^ (c & 7);
        bsrc[i] = G + (size_t)(r0 + c) * K + q * 8;
    }

    for (int k0 = 0; k0 < K; k0 += 64) {
        gl_lds16(Xr0 + k0, (void*)(As + tid * 8));
        gl_lds16(Xr1 + k0, (void*)(As + ((size_t)tid + 512) * 8));
#pragma unroll
        for (int i = 0; i < 4; ++i)
            gl_lds16(bsrc[i] + k0, (void*)(Bs + ((size_t)i * 512 + tid) * 8));
        __syncthreads();
#pragma unroll
        for (int kk = 0; kk < 2; ++kk) {
            bf16x8 af[4], bfr[4];
#pragma unroll
            for (int rt = 0; rt < 4; ++rt) {
                int sr = wn * 64 + rt * 16 + m;
                int slot = sr * 8 + ((kk * 4 + qd) ^ (sr & 7));
                af[rt] = *(const bf16x8*)(Bs + slot * 8);
            }
#pragma unroll
            for (int ct = 0; ct < 4; ++ct) {
                int br = wb * 64 + ct * 16 + m;
                int slot = br * 8 + ((kk * 4 + qd) ^ (br & 7));
                bfr[ct] = *(const bf16x8*)(As + slot * 8);
            }
#pragma unroll
            for (int rt = 0; rt < 4; ++rt)
#pragma unroll
                for (int ct = 0; ct < 4; ++ct)
                    acc[rt][ct] = __builtin_amdgcn_mfma_f32_16x16x32_bf16(
                        af[rt], bfr[ct], acc[rt][ct], 0, 0, 0);
        }
        __syncthreads();
    }

#pragma unroll
    for (int rt = 0; rt < 4; ++rt)
#pragma unroll
        for (int ct = 0; ct < 4; ++ct)
#pragma unroll
            for (int reg = 0; reg < 4; ++reg) {
                int rl = wn * 64 + rt * 16 + qd * 4 + reg;
                int el = wb * 64 + ct * 16 + m;
                size_t gi = (size_t)(r0 + rl) * K + (e0 + el);
                W[gi] = __float2bfloat16(
                    __bfloat162float(G[gi]) + 0.1f * acc[rt][ct][reg]);
            }
}

// ---------- output head: y = t2 @ Wfin + bout ----------

__global__ __launch_bounds__(256) void out_head(
    const __hip_bfloat16* __restrict__ t2,   // [B][64] bf16
    const float* __restrict__ Wfin,          // [64][12] f32
    const float* __restrict__ bout,          // [12]
    float* __restrict__ y)                   // [B][12]
{
    __shared__ float hb[16][65];
    __shared__ float wf[768];
    __shared__ float bo[12];

    const int tid = threadIdx.x;
    const int row0 = blockIdx.x * 16;

#pragma unroll
    for (int i = 0; i < 4; ++i) {
        int idx = tid + i * 256;
        int r = idx >> 6;
        int c = idx & 63;
        hb[r][c] = __bfloat162float(t2[(size_t)(row0 + r) * 64 + c]);
    }
#pragma unroll
    for (int i = 0; i < 3; ++i)
        wf[tid + 256 * i] = Wfin[tid + 256 * i];
    if (tid < 12) bo[tid] = bout[tid];
    __syncthreads();

    if (tid < 192) {
        int r = tid / 12, o = tid - 12 * r;
        float acc = bo[o];
#pragma unroll
        for (int k = 0; k < 64; ++k)
            acc += hb[r][k] * wf[k * 12 + o];
        y[(size_t)(row0 + r) * 12 + o] = acc;
    }
}

// ---------- fp32 fallback path (round-2 verified) ----------

__global__ __launch_bounds__(256) void liquid_proj_f32(
    const float* __restrict__ x, const float* __restrict__ Wi,
    const float* __restrict__ bi, const float* __restrict__ bl,
    const float* __restrict__ Wo, const float* __restrict__ bo,
    float* __restrict__ t, int K, int Nn)
{
    __shared__ float xs[16][65];
    __shared__ float ws[16][65];
    const int tid = threadIdx.x;
    const int tx = tid & 15, ty = tid >> 4;
    const int row0 = blockIdx.x * 64;
    const int n = blockIdx.y;
    const float* Wn = Wi + (size_t)n * K * 64;
    float acc[4][4] = {};
    for (int k0 = 0; k0 < K; k0 += 16) {
#pragma unroll
        for (int i = 0; i < 4; ++i) {
            int li = tid + 256 * i;
            xs[li & 15][li >> 4] = x[(size_t)(row0 + (li >> 4)) * K + k0 + (li & 15)];
        }
#pragma unroll
        for (int i = 0; i < 4; ++i) {
            int li = tid + 256 * i;
            ws[li >> 6][li & 63] = Wn[(size_t)(k0 + (li >> 6)) * 64 + (li & 63)];
        }
        __syncthreads();
#pragma unroll
        for (int kk = 0; kk < 16; ++kk) {
            float xa[4], wb[4];
#pragma unroll
            for (int i = 0; i < 4; ++i) xa[i] = xs[kk][4 * ty + i];
#pragma unroll
            for (int j = 0; j < 4; ++j) wb[j] = ws[kk][4 * tx + j];
#pragma unroll
            for (int i = 0; i < 4; ++i)
#pragma unroll
                for (int j = 0; j < 4; ++j) acc[i][j] += xa[i] * wb[j];
        }
        __syncthreads();
    }
    float part[4] = {0.f, 0.f, 0.f, 0.f};
#pragma unroll
    for (int j = 0; j < 4; ++j) {
        int cc = 4 * tx + j;
        float bias = bi[n * 64 + cc] + bl[n * 64 + cc];
        float wov = Wo[n * 64 + cc];
#pragma unroll
        for (int i = 0; i < 4; ++i) {
            float v = acc[i][j] + bias;
            part[i] += (tanhf(v) + 0.1f * sinf(0.5f * v) * cosf(0.3f * v)) * wov;
        }
    }
#pragma unroll
    for (int mk = 1; mk < 16; mk <<= 1)
#pragma unroll
        for (int i = 0; i < 4; ++i) part[i] += __shfl_xor(part[i], mk, 64);
    if (tx == 0) {
        float b = bo[n];
#pragma unroll
        for (int i = 0; i < 4; ++i)
            t[(size_t)(row0 + 4 * ty + i) * Nn + n] = part[i] + b;
    }
}

__global__ void lateral_f32_kernel(const float* __restrict__ t,
                                   const float* __restrict__ L,
                                   const float* __restrict__ a,
                                   float* __restrict__ h, int Nn)
{
    extern __shared__ float tb[];
    const int b = blockIdx.x;
    const int n = threadIdx.x;
    tb[n] = t[(size_t)b * Nn + n];
    __syncthreads();
    float acc = 0.f;
    for (int mm = 0; mm < Nn; ++mm)
        acc += tb[mm] * L[(size_t)mm * Nn + n];
    h[(size_t)b * Nn + n] = (tb[n] + 0.1f * acc) * a[n];
}

__global__ void out_f32_kernel(const float* __restrict__ h,
                               const float* __restrict__ Wout,
                               const float* __restrict__ bout,
                               float* __restrict__ y)
{
    int g = blockIdx.x * blockDim.x + threadIdx.x;
    if (g >= BATCH * 12) return;
    int b = g / 12, o = g - 12 * b;
    float acc = bout[o];
    const float* hb = h + (size_t)b * 64;
#pragma unroll
    for (int k = 0; k < 64; ++k) acc += hb[k] * Wout[k * 12 + o];
    y[g] = acc;
}

extern "C" void kernel_launch(void* const* d_in, const int* in_sizes, int n_in,
                              void* d_out, int out_size, void* d_ws, size_t ws_size,
                              hipStream_t stream)
{
    (void)in_sizes; (void)n_in; (void)out_size;
    const float* x = (const float*)d_in[0];
    const float* Wout = (const float*)d_in[22];
    const float* bout = (const float*)d_in[23];
    const int dims[4] = {512, 256, 128, 64};
    char* ws = (char*)d_ws;
    const size_t MB = 1024u * 1024u;
    const size_t KB = 1024u;

    if (ws_size >= 28 * MB) {
        // Layout (28 MB) — identical to r16 (verified):
        //   [0,16)   Wt0 ; after proj0: t1 @0 (1MB), W2f @2 (1MB), t2 @4
        //   [16,20)  G1 ; [20,21) G2 ; [21,25) xb -> W1f after proj0
        //   [25,27)  t0 ; [27,..) Tg(4KB), Lb0 @+16KB, Lb1 @+160KB,
        //   Wfin @+256KB (3KB)
        __hip_bfloat16* Wt0 = (__hip_bfloat16*)ws;
        __hip_bfloat16* G1  = (__hip_bfloat16*)(ws + 16 * MB);
        __hip_bfloat16* G2  = (__hip_bfloat16*)(ws + 20 * MB);
        __hip_bfloat16* xb  = (__hip_bfloat16*)(ws + 21 * MB);
        __hip_bfloat16* W1f = (__hip_bfloat16*)(ws + 21 * MB);
        __hip_bfloat16* t0  = (__hip_bfloat16*)(ws + 25 * MB);
        __hip_bfloat16* t1  = (__hip_bfloat16*)ws;
        __hip_bfloat16* W2f = (__hip_bfloat16*)(ws + 2 * MB);
        __hip_bfloat16* t2  = (__hip_bfloat16*)(ws + 4 * MB);
        float* Tg = (float*)(ws + 27 * MB);
        __hip_bfloat16* Lb0 = (__hip_bfloat16*)(ws + 27 * MB + 16 * KB);
        __hip_bfloat16* Lb1 = (__hip_bfloat16*)(ws + 27 * MB + 160 * KB);
        float* Wfin = (float*)(ws + 27 * MB + 256 * KB);

        const float* a0 = (const float*)d_in[7];
        const float* a1 = (const float*)d_in[14];
        const float* L0 = (const float*)d_in[6];
        const float* L1 = (const float*)d_in[13];
        const float* L2 = (const float*)d_in[20];
        const float* a2 = (const float*)d_in[21];

        conv_all<<<4818, 256, 0, stream>>>(
            x, xb, (const float*)d_in[1], (const float*)d_in[8],
            (const float*)d_in[15], a0, a1, L0, L1, L2, a2, Wout,
            Wt0, G1, G2, Lb0, Lb1, Tg, Wfin);

        // layer 0
        liquid_proj_mfma<<<2048, 512, 0, stream>>>(
            xb, Wt0, (const float*)d_in[2], (const float*)d_in[3],
            (const float*)d_in[4], (const float*)d_in[5], Tg, t0, 512, 256);

        // fold laterals 0,1 into W1f/W2f (xb & Wt0 regions now free)
        fold_lateral<<<80, 512, 0, stream>>>(G1, Lb0, W1f, G2, Lb1, W2f);

        // layer 1 (lateral0 folded)
        liquid_proj_mfma<<<1024, 512, 0, stream>>>(
            t0, W1f, (const float*)d_in[9], (const float*)d_in[10],
            (const float*)d_in[11], (const float*)d_in[12], Tg, t1, 256, 128);

        // layer 2 (lateral1 folded)
        liquid_proj_mfma<<<512, 512, 0, stream>>>(
            t1, W2f, (const float*)d_in[16], (const float*)d_in[17],
            (const float*)d_in[18], (const float*)d_in[19], Tg, t2, 128, 64);

        // output head (final lateral folded into Wfin)
        out_head<<<BATCH / 16, 256, 0, stream>>>(t2, Wfin, bout, (float*)d_out);
    } else {
        float* tbufs[3] = {(float*)ws, (float*)ws, (float*)(ws + 4 * MB)};
        float* hs[3] = {(float*)(ws + 4 * MB), (float*)(ws + 2 * MB),
                        (float*)(ws + 5 * MB)};
        const float* prev = x;
        for (int l = 0; l < 3; ++l) {
            const float* Wi = (const float*)d_in[1 + 7 * l + 0];
            const float* bi = (const float*)d_in[1 + 7 * l + 1];
            const float* bl = (const float*)d_in[1 + 7 * l + 2];
            const float* Wo = (const float*)d_in[1 + 7 * l + 3];
            const float* bo = (const float*)d_in[1 + 7 * l + 4];
            const float* L  = (const float*)d_in[1 + 7 * l + 5];
            const float* a  = (const float*)d_in[1 + 7 * l + 6];
            const int K = dims[l], Nn = dims[l + 1];
            liquid_proj_f32<<<dim3(BATCH / 64, Nn), 256, 0, stream>>>(
                prev, Wi, bi, bl, Wo, bo, tbufs[l], K, Nn);
            lateral_f32_kernel<<<BATCH, Nn, Nn * sizeof(float), stream>>>(
                tbufs[l], L, a, hs[l], Nn);
            prev = hs[l];
        }
        out_f32_kernel<<<(BATCH * 12 + 255) / 256, 256, 0, stream>>>(
            hs[2], Wout, bout, (float*)d_out);
    }
}